// Round 6
// baseline (74.200 us; speedup 1.0000x reference)
//
#include <hip/hip_runtime.h>
#include <math.h>

#define BB 4
#define TT 4096
#define CC 1024
#define HH 64
#define MM (BB*TT)

typedef __attribute__((ext_vector_type(8))) short  short8;
typedef __attribute__((ext_vector_type(4))) short  short4v;
typedef __attribute__((ext_vector_type(4))) float  f32x4;

static __device__ __forceinline__ unsigned short f2bf(float f) {
    union { float f; unsigned u; } v; v.f = f;
    unsigned r = v.u + 0x7FFF + ((v.u >> 16) & 1);
    return (unsigned short)(r >> 16);
}

// ---------------- Kernel 0: W -> W^T bf16 (tiny) ----------------
__global__ __launch_bounds__(256) void convw_kernel(
        const float* __restrict__ Wq, const float* __restrict__ Wk,
        const float* __restrict__ Wv, unsigned short* __restrict__ wtb) {
    __shared__ unsigned short sW[64][66];
    const int m    = blockIdx.x >> 4;
    const int cblk = blockIdx.x & 15;
    const float* W = (m == 0) ? Wq : (m == 1) ? Wk : Wv;
    const int lane = threadIdx.x & 63;
    const int w    = threadIdx.x >> 6;
    #pragma unroll
    for (int rep = 0; rep < 16; ++rep) {
        const int cl = w * 16 + rep;
        sW[cl][lane] = f2bf(W[(size_t)(cblk * 64 + cl) * HH + lane]);
    }
    __syncthreads();
    #pragma unroll
    for (int rep = 0; rep < 16; ++rep) {
        const int h2 = w * 16 + rep;
        wtb[(size_t)(m * 64 + h2) * CC + cblk * 64 + lane] = sW[lane][h2];
    }
}

// ---------------- Kernel 1: burst-staged, barrier-free MFMA projection ----
// BM=32, BN=192. grid=512, 512 threads = 8 waves (2 rg x 4 cg).
// Phase 1: whole A-tile (32x1024 fp32) burst-loaded (16 indep float4/thread),
//          cvt->bf16 into LDS (row stride 2064B: bank-quad = 129r mod 8).
// Phase 2: NO barriers. A from LDS, B global->reg (L2-hot), depth-2 prefetch.
__global__ __launch_bounds__(512, 4) void gemm_kernel(
        const float* __restrict__ x,
        const unsigned short* __restrict__ wtb,
        unsigned short* __restrict__ qb,
        unsigned short* __restrict__ kb,
        unsigned short* __restrict__ vt) {
    __shared__ unsigned short As[32 * 1032];   // 66 KB, row stride 2064 B

    const int tid  = threadIdx.x;
    const int lane = tid & 63;
    const int w    = tid >> 6;
    const int l15  = lane & 15;
    const int lg   = lane >> 4;
    const int row0 = blockIdx.x * 32;
    const int rg   = (w >> 2) * 16;      // row group: 0 or 16
    const int wc   = (w & 3) * 48;       // col group base

    // ---- Phase 1: stage A ----
    {
        const int r  = tid & 31;         // row within tile
        const int og = tid >> 5;         // octet-group 0..15 (8 octets each)
        const float* xs = x + (size_t)(row0 + r) * CC + og * 64;
        float4 xv[16];
        #pragma unroll
        for (int j = 0; j < 16; ++j)
            xv[j] = *reinterpret_cast<const float4*>(xs + j * 4);
        char* dst = (char*)As + r * 2064 + og * 128;
        #pragma unroll
        for (int j = 0; j < 8; ++j) {
            short8 o;
            o[0] = (short)f2bf(xv[2*j].x);   o[1] = (short)f2bf(xv[2*j].y);
            o[2] = (short)f2bf(xv[2*j].z);   o[3] = (short)f2bf(xv[2*j].w);
            o[4] = (short)f2bf(xv[2*j+1].x); o[5] = (short)f2bf(xv[2*j+1].y);
            o[6] = (short)f2bf(xv[2*j+1].z); o[7] = (short)f2bf(xv[2*j+1].w);
            *reinterpret_cast<short8*>(dst + j * 16) = o;
        }
    }
    __syncthreads();   // the only block-wide sync

    // ---- Phase 2: K-loop, no barriers ----
    f32x4 acc[3];
    #pragma unroll
    for (int j = 0; j < 3; ++j) acc[j] = (f32x4){0.f, 0.f, 0.f, 0.f};

    const char* Arow = (const char*)As + (rg + l15) * 2064 + lg * 16;
    // B pointers: n = wc + nf*16 + l15
    const unsigned short* bp0 = wtb + (size_t)(wc +  0 + l15) * CC + lg * 8;
    const unsigned short* bp1 = wtb + (size_t)(wc + 16 + l15) * CC + lg * 8;
    const unsigned short* bp2 = wtb + (size_t)(wc + 32 + l15) * CC + lg * 8;

    short8 afc[2], afn[2], bfc[3][2], bfn[3][2];
    #pragma unroll
    for (int kh = 0; kh < 2; ++kh) {
        afc[kh]    = *(const short8*)(Arow + kh * 64);
        bfc[0][kh] = *(const short8*)(bp0 + kh * 32);
        bfc[1][kh] = *(const short8*)(bp1 + kh * 32);
        bfc[2][kh] = *(const short8*)(bp2 + kh * 32);
    }

    #pragma unroll
    for (int t = 0; t < 16; ++t) {
        if (t < 15) {
            const int ko = (t + 1) * 64;
            #pragma unroll
            for (int kh = 0; kh < 2; ++kh) {
                afn[kh]    = *(const short8*)(Arow + t * 128 + 128 + kh * 64);
                bfn[0][kh] = *(const short8*)(bp0 + ko + kh * 32);
                bfn[1][kh] = *(const short8*)(bp1 + ko + kh * 32);
                bfn[2][kh] = *(const short8*)(bp2 + ko + kh * 32);
            }
        }
        #pragma unroll
        for (int kh = 0; kh < 2; ++kh)
            #pragma unroll
            for (int nf = 0; nf < 3; ++nf)
                acc[nf] = __builtin_amdgcn_mfma_f32_16x16x32_bf16(
                    afc[kh], bfc[nf][kh], acc[nf], 0, 0, 0);
        #pragma unroll
        for (int kh = 0; kh < 2; ++kh) {
            afc[kh] = afn[kh];
            #pragma unroll
            for (int nf = 0; nf < 3; ++nf) bfc[nf][kh] = bfn[nf][kh];
        }
    }

    // ---- epilogue: q,k row-major bf16; v transposed vt[b][h][t] ----
    const int b = row0 >> 12;
    #pragma unroll
    for (int nf = 0; nf < 3; ++nf) {
        const int ng = wc + nf * 16 + l15;
        const int m  = ng >> 6, h = ng & 63;
        const int rowbase = row0 + rg + lg * 4;
        if (m == 2) {
            short4v pk;
            pk[0] = (short)f2bf(acc[nf][0]);
            pk[1] = (short)f2bf(acc[nf][1]);
            pk[2] = (short)f2bf(acc[nf][2]);
            pk[3] = (short)f2bf(acc[nf][3]);
            *reinterpret_cast<short4v*>(
                &vt[((size_t)(b * 64 + h)) * TT + (rowbase & (TT - 1))]) = pk;
        } else {
            unsigned short* dst = (m == 0) ? qb : kb;
            #pragma unroll
            for (int r = 0; r < 4; ++r)
                dst[(size_t)(rowbase + r) * HH + h] = f2bf(acc[nf][r]);
        }
    }
}

// ---------------- Kernel 2: MFMA windowed causal attention ----------------
// (unchanged from round 4/5)
__global__ __launch_bounds__(256) void attn_kernel(
        const unsigned short* __restrict__ qb,
        const unsigned short* __restrict__ kb,
        const unsigned short* __restrict__ vt,
        const float* __restrict__ decay,
        float* __restrict__ out) {
    __shared__ unsigned short P[4][16 * 168];

    const int lane = threadIdx.x & 63;
    const int w    = threadIdx.x >> 6;
    const int l15  = lane & 15;
    const int lg   = lane >> 4;
    const int qt   = blockIdx.x * 4 + w;
    const int gb   = qt >> 8;
    const int i0   = (qt & 255) << 4;

    const float dec = fabsf(decay[0]);
    const size_t bbase = (size_t)gb * TT;

    short8 af0, af1;
    {
        const unsigned short* qp = qb + (bbase + i0 + l15) * HH + lg * 8;
        af0 = *(const short8*)(qp);
        af1 = *(const short8*)(qp + 32);
    }

    float psum[4] = {0.f, 0.f, 0.f, 0.f};
    unsigned short* Pw = &P[w][0];

    if (i0 >= 144) {
        const int js = i0 - 144;
        const unsigned short* kp = kb + (bbase + js + l15) * HH + lg * 8;
        #pragma unroll
        for (int ts = 0; ts < 10; ++ts) {
            short8 b0 = *(const short8*)(kp + (size_t)ts * 16 * HH);
            short8 b1 = *(const short8*)(kp + (size_t)ts * 16 * HH + 32);
            f32x4 s = (f32x4){0.f, 0.f, 0.f, 0.f};
            s = __builtin_amdgcn_mfma_f32_16x16x32_bf16(af0, b0, s, 0, 0, 0);
            s = __builtin_amdgcn_mfma_f32_16x16x32_bf16(af1, b1, s, 0, 0, 0);
            const int d0 = 144 + lg * 4 - ts * 16 - l15;
            #pragma unroll
            for (int r = 0; r < 4; ++r) {
                const int d = d0 + r;
                float sv = s[r] * 0.125f - dec * (float)d - 12.0f;
                float p  = (ts == 9 && d < 0) ? 0.0f : __expf(sv);
                psum[r] += p;
                Pw[(lg * 4 + r) * 168 + ts * 16 + l15] = f2bf(p);
            }
        }
        #pragma unroll
        for (int off = 1; off < 16; off <<= 1)
            #pragma unroll
            for (int r = 0; r < 4; ++r)
                psum[r] += __shfl_xor(psum[r], off, 64);

        asm volatile("s_waitcnt lgkmcnt(0)" ::: "memory");
        __builtin_amdgcn_sched_barrier(0);

        f32x4 oacc[4];
        #pragma unroll
        for (int ht = 0; ht < 4; ++ht) oacc[ht] = (f32x4){0.f, 0.f, 0.f, 0.f};
        const unsigned short* vp = vt + ((size_t)(gb * 64) + l15) * TT + js + lg * 8;

        __builtin_amdgcn_s_setprio(1);
        #pragma unroll
        for (int kt = 0; kt < 5; ++kt) {
            short8 pa = *(const short8*)((const char*)Pw + l15 * 336 + kt * 64 + lg * 16);
            #pragma unroll
            for (int ht = 0; ht < 4; ++ht) {
                short8 bv = *(const short8*)(vp + (size_t)ht * 16 * TT + kt * 32);
                oacc[ht] = __builtin_amdgcn_mfma_f32_16x16x32_bf16(pa, bv, oacc[ht], 0, 0, 0);
            }
        }
        __builtin_amdgcn_s_setprio(0);

        float inv[4];
        #pragma unroll
        for (int r = 0; r < 4; ++r) inv[r] = 1.0f / psum[r];
        float* op = out + (bbase + i0 + lg * 4) * HH + l15;
        #pragma unroll
        for (int ht = 0; ht < 4; ++ht)
            #pragma unroll
            for (int r = 0; r < 4; ++r)
                op[(size_t)r * HH + ht * 16] = oacc[ht][r] * inv[r];
    } else {
        const int NS = (i0 >> 4) + 1;
        const int NK = (NS + 1) >> 1;
        const int dbase = i0 + lg * 4 - l15;
        const unsigned short* kp = kb + (bbase + l15) * HH + lg * 8;

        for (int ts = 0; ts < NS; ++ts) {
            short8 b0 = *(const short8*)(kp);
            short8 b1 = *(const short8*)(kp + 32);
            kp += 16 * HH;
            f32x4 s = (f32x4){0.f, 0.f, 0.f, 0.f};
            s = __builtin_amdgcn_mfma_f32_16x16x32_bf16(af0, b0, s, 0, 0, 0);
            s = __builtin_amdgcn_mfma_f32_16x16x32_bf16(af1, b1, s, 0, 0, 0);
            const int d0 = dbase - ts * 16;
            #pragma unroll
            for (int r = 0; r < 4; ++r) {
                const int d = d0 + r;
                float sv = s[r] * 0.125f - dec * (float)d - 12.0f;
                float p  = (d < 0) ? 0.0f : __expf(sv);
                psum[r] += p;
                Pw[(lg * 4 + r) * 168 + ts * 16 + l15] = f2bf(p);
            }
        }
        if (NS & 1) {
            #pragma unroll
            for (int r = 0; r < 4; ++r)
                Pw[(lg * 4 + r) * 168 + NS * 16 + l15] = 0;
        }
        #pragma unroll
        for (int off = 1; off < 16; off <<= 1)
            #pragma unroll
            for (int r = 0; r < 4; ++r)
                psum[r] += __shfl_xor(psum[r], off, 64);

        asm volatile("s_waitcnt lgkmcnt(0)" ::: "memory");
        __builtin_amdgcn_sched_barrier(0);

        f32x4 oacc[4];
        #pragma unroll
        for (int ht = 0; ht < 4; ++ht) oacc[ht] = (f32x4){0.f, 0.f, 0.f, 0.f};
        const unsigned short* vp = vt + ((size_t)(gb * 64) + l15) * TT + lg * 8;

        for (int kt = 0; kt < NK; ++kt) {
            short8 pa = *(const short8*)((const char*)Pw + l15 * 336 + kt * 64 + lg * 16);
            #pragma unroll
            for (int ht = 0; ht < 4; ++ht) {
                short8 bv = *(const short8*)(vp + (size_t)ht * 16 * TT + kt * 32);
                oacc[ht] = __builtin_amdgcn_mfma_f32_16x16x32_bf16(pa, bv, oacc[ht], 0, 0, 0);
            }
        }

        float inv[4];
        #pragma unroll
        for (int r = 0; r < 4; ++r) inv[r] = 1.0f / psum[r];
        float* op = out + (bbase + i0 + lg * 4) * HH + l15;
        #pragma unroll
        for (int ht = 0; ht < 4; ++ht)
            #pragma unroll
            for (int r = 0; r < 4; ++r)
                op[(size_t)r * HH + ht * 16] = oacc[ht][r] * inv[r];
    }
}

extern "C" void kernel_launch(void* const* d_in, const int* in_sizes, int n_in,
                              void* d_out, int out_size, void* d_ws, size_t ws_size,
                              hipStream_t stream) {
    const float* x     = (const float*)d_in[0];
    const float* Wq    = (const float*)d_in[1];
    const float* Wk    = (const float*)d_in[2];
    const float* Wv    = (const float*)d_in[3];
    const float* decay = (const float*)d_in[4];
    float* out = (float*)d_out;

    unsigned short* qb  = (unsigned short*)d_ws;          // 2 MB
    unsigned short* kb  = qb + (size_t)MM * HH;           // 2 MB
    unsigned short* vt  = kb + (size_t)MM * HH;           // 2 MB (transposed)
    unsigned short* wtb = vt + (size_t)MM * HH;           // 384 KB

    convw_kernel<<<48, 256, 0, stream>>>(Wq, Wk, Wv, wtb);
    gemm_kernel<<<MM / 32, 512, 0, stream>>>(x, wtb, qb, kb, vt);
    attn_kernel<<<MM / 64, 256, 0, stream>>>(qb, kb, vt, decay, out);
}

// Round 7
// 45.993 us; speedup vs baseline: 1.6133x; 1.6133x over previous
//
#include <hip/hip_runtime.h>
#include <math.h>

#define BB 4
#define TT 4096
#define CC 1024
#define HH 64
#define MM (BB*TT)

typedef __attribute__((ext_vector_type(8))) short  short8;
typedef __attribute__((ext_vector_type(4))) short  short4v;
typedef __attribute__((ext_vector_type(4))) float  f32x4;

typedef const __attribute__((address_space(1))) unsigned int GU;
typedef __attribute__((address_space(3))) unsigned int LU;

static __device__ __forceinline__ unsigned short f2bf(float f) {
    union { float f; unsigned u; } v; v.f = f;
    unsigned r = v.u + 0x7FFF + ((v.u >> 16) & 1);
    return (unsigned short)(r >> 16);
}

// ---------------- Kernel 0: W -> W^T bf16 (tiny) ----------------
__global__ __launch_bounds__(256) void convw_kernel(
        const float* __restrict__ Wq, const float* __restrict__ Wk,
        const float* __restrict__ Wv, unsigned short* __restrict__ wtb) {
    __shared__ unsigned short sW[64][66];
    const int m    = blockIdx.x >> 4;
    const int cblk = blockIdx.x & 15;
    const float* W = (m == 0) ? Wq : (m == 1) ? Wk : Wv;
    const int lane = threadIdx.x & 63;
    const int w    = threadIdx.x >> 6;
    #pragma unroll
    for (int rep = 0; rep < 16; ++rep) {
        const int cl = w * 16 + rep;
        sW[cl][lane] = f2bf(W[(size_t)(cblk * 64 + cl) * HH + lane]);
    }
    __syncthreads();
    #pragma unroll
    for (int rep = 0; rep < 16; ++rep) {
        const int h2 = w * 16 + rep;
        wtb[(size_t)(m * 64 + h2) * CC + cblk * 64 + lane] = sW[lane][h2];
    }
}

// ---------------- Kernel 1: r2-structure MFMA projection, fp32-A DMA ------
// C[16384][192] = x[16384][1024] (fp32, cvt at read) * W[1024][192].
// BM=64, BN=192, BK=64. grid=256, 256 threads = 4 waves (wave w: cols w*48).
// A: fp32 global_load_lds, 16-slot XOR swizzle folded into GLOBAL source
//    (LDS dest linear, per m173); cvt fp32->bf16 at LDS->fragment read.
// B: bf16 global_load_lds, 8-slot XOR swizzle (verbatim round-2 path).
// Plain __syncthreads drain loop -- the empirically fastest structure.
__global__ __launch_bounds__(256) void gemm_kernel(
        const float* __restrict__ x,
        const unsigned short* __restrict__ wtb,
        unsigned short* __restrict__ qb,
        unsigned short* __restrict__ kb,
        unsigned short* __restrict__ vt) {
    __shared__ float          As[64 * 64];    // 16 KB fp32, row = 256 B
    __shared__ unsigned short Bs[192 * 64];   // 24 KB bf16, row = 128 B

    const int tid  = threadIdx.x;
    const int lane = tid & 63;
    const int w    = tid >> 6;
    const int l15  = lane & 15;
    const int lg   = lane >> 4;
    const int row0 = blockIdx.x * 64;

    f32x4 acc[4][3];
    #pragma unroll
    for (int i = 0; i < 4; ++i)
        #pragma unroll
        for (int j = 0; j < 3; ++j)
            acc[i][j] = (f32x4){0.f, 0.f, 0.f, 0.f};

    // A staging map (pass p of 4): row r = p*16 + (tid>>4), slot s = tid&15.
    // LDS holds logical 16B-slot l at position l ^ (r&15)  =>  source slot
    // for position s is s ^ (r&15);  r&15 == tid>>4 for all p.
    const int arow_local = tid >> 4;                 // r & 15
    const int aslot      = (tid & 15) ^ arow_local;  // source 16B slot
    const float* asrc0   = x + (size_t)(row0 + arow_local) * CC + aslot * 4;

    const int bbyte0 = w * 1024 + lane * 16;
    const int swz    = (l15 & 7) << 4;

    for (int kc = 0; kc < CC; kc += 64) {
        // ---- stage A: 16 KB fp32, 4 DMA passes ----
        #pragma unroll
        for (int p = 0; p < 4; ++p) {
            const float* g = asrc0 + (size_t)p * 16 * CC + kc;
            __builtin_amdgcn_global_load_lds((GU*)g,
                (LU*)((char*)As + p * 4096 + w * 1024), 16, 0, 0);
        }
        // ---- stage B: 24 KB bf16, 6 DMA passes (verbatim r2) ----
        #pragma unroll
        for (int it = 0; it < 6; ++it) {
            const int lidx = it * 4096 + bbyte0;
            const int r  = lidx >> 7;
            const int cb = (((lidx & 127) >> 4) ^ (r & 7));
            const unsigned short* g = wtb + (size_t)r * CC + kc + cb * 8;
            __builtin_amdgcn_global_load_lds((GU*)g,
                (LU*)((char*)Bs + it * 4096 + w * 1024), 16, 0, 0);
        }
        __syncthreads();   // drain: tile ready

        const char* Asc = (const char*)As;
        const char* Bsc = (const char*)Bs;

        // A fragments: fp32 read + cvt (slot pos = l16 ^ l15, pair pos^1)
        short8 af[4][2];
        #pragma unroll
        for (int mf = 0; mf < 4; ++mf)
            #pragma unroll
            for (int kh = 0; kh < 2; ++kh) {
                const int r    = mf * 16 + l15;
                const int l16  = kh * 8 + lg * 2;
                const int pos0 = l16 ^ l15;
                const float4 lo = *(const float4*)(Asc + r * 256 + pos0 * 16);
                const float4 hi = *(const float4*)(Asc + r * 256 + (pos0 ^ 1) * 16);
                short8 a;
                a[0] = (short)f2bf(lo.x); a[1] = (short)f2bf(lo.y);
                a[2] = (short)f2bf(lo.z); a[3] = (short)f2bf(lo.w);
                a[4] = (short)f2bf(hi.x); a[5] = (short)f2bf(hi.y);
                a[6] = (short)f2bf(hi.z); a[7] = (short)f2bf(hi.w);
                af[mf][kh] = a;
            }
        short8 bf[3][2];
        #pragma unroll
        for (int nf = 0; nf < 3; ++nf)
            #pragma unroll
            for (int kh = 0; kh < 2; ++kh) {
                const int n = w * 48 + nf * 16 + l15;
                bf[nf][kh] = *(const short8*)(Bsc + n * 128 + ((kh * 64 + lg * 16) ^ swz));
            }
        #pragma unroll
        for (int kh = 0; kh < 2; ++kh)
            #pragma unroll
            for (int mf = 0; mf < 4; ++mf)
                #pragma unroll
                for (int nf = 0; nf < 3; ++nf)
                    acc[mf][nf] = __builtin_amdgcn_mfma_f32_16x16x32_bf16(
                        af[mf][kh], bf[nf][kh], acc[mf][nf], 0, 0, 0);
        __syncthreads();   // protect LDS before next DMA
    }

    // ---- epilogue: q,k row-major bf16; v transposed vt[b][h][t] ----
    const int b = row0 >> 12;
    #pragma unroll
    for (int mf = 0; mf < 4; ++mf)
        #pragma unroll
        for (int nf = 0; nf < 3; ++nf) {
            const int ng = w * 48 + nf * 16 + l15;
            const int m  = ng >> 6, h = ng & 63;
            const int rowbase = row0 + mf * 16 + lg * 4;
            if (m == 2) {
                short4v pk;
                pk[0] = (short)f2bf(acc[mf][nf][0]);
                pk[1] = (short)f2bf(acc[mf][nf][1]);
                pk[2] = (short)f2bf(acc[mf][nf][2]);
                pk[3] = (short)f2bf(acc[mf][nf][3]);
                *reinterpret_cast<short4v*>(
                    &vt[((size_t)(b * 64 + h)) * TT + (rowbase & (TT - 1))]) = pk;
            } else {
                unsigned short* dst = (m == 0) ? qb : kb;
                #pragma unroll
                for (int r = 0; r < 4; ++r)
                    dst[(size_t)(rowbase + r) * HH + h] = f2bf(acc[mf][nf][r]);
            }
        }
}

// ---------------- Kernel 2: MFMA windowed causal attention ----------------
// (unchanged from round 4/5/6)
__global__ __launch_bounds__(256) void attn_kernel(
        const unsigned short* __restrict__ qb,
        const unsigned short* __restrict__ kb,
        const unsigned short* __restrict__ vt,
        const float* __restrict__ decay,
        float* __restrict__ out) {
    __shared__ unsigned short P[4][16 * 168];

    const int lane = threadIdx.x & 63;
    const int w    = threadIdx.x >> 6;
    const int l15  = lane & 15;
    const int lg   = lane >> 4;
    const int qt   = blockIdx.x * 4 + w;
    const int gb   = qt >> 8;
    const int i0   = (qt & 255) << 4;

    const float dec = fabsf(decay[0]);
    const size_t bbase = (size_t)gb * TT;

    short8 af0, af1;
    {
        const unsigned short* qp = qb + (bbase + i0 + l15) * HH + lg * 8;
        af0 = *(const short8*)(qp);
        af1 = *(const short8*)(qp + 32);
    }

    float psum[4] = {0.f, 0.f, 0.f, 0.f};
    unsigned short* Pw = &P[w][0];

    if (i0 >= 144) {
        const int js = i0 - 144;
        const unsigned short* kp = kb + (bbase + js + l15) * HH + lg * 8;
        #pragma unroll
        for (int ts = 0; ts < 10; ++ts) {
            short8 b0 = *(const short8*)(kp + (size_t)ts * 16 * HH);
            short8 b1 = *(const short8*)(kp + (size_t)ts * 16 * HH + 32);
            f32x4 s = (f32x4){0.f, 0.f, 0.f, 0.f};
            s = __builtin_amdgcn_mfma_f32_16x16x32_bf16(af0, b0, s, 0, 0, 0);
            s = __builtin_amdgcn_mfma_f32_16x16x32_bf16(af1, b1, s, 0, 0, 0);
            const int d0 = 144 + lg * 4 - ts * 16 - l15;
            #pragma unroll
            for (int r = 0; r < 4; ++r) {
                const int d = d0 + r;
                float sv = s[r] * 0.125f - dec * (float)d - 12.0f;
                float p  = (ts == 9 && d < 0) ? 0.0f : __expf(sv);
                psum[r] += p;
                Pw[(lg * 4 + r) * 168 + ts * 16 + l15] = f2bf(p);
            }
        }
        #pragma unroll
        for (int off = 1; off < 16; off <<= 1)
            #pragma unroll
            for (int r = 0; r < 4; ++r)
                psum[r] += __shfl_xor(psum[r], off, 64);

        asm volatile("s_waitcnt lgkmcnt(0)" ::: "memory");
        __builtin_amdgcn_sched_barrier(0);

        f32x4 oacc[4];
        #pragma unroll
        for (int ht = 0; ht < 4; ++ht) oacc[ht] = (f32x4){0.f, 0.f, 0.f, 0.f};
        const unsigned short* vp = vt + ((size_t)(gb * 64) + l15) * TT + js + lg * 8;

        __builtin_amdgcn_s_setprio(1);
        #pragma unroll
        for (int kt = 0; kt < 5; ++kt) {
            short8 pa = *(const short8*)((const char*)Pw + l15 * 336 + kt * 64 + lg * 16);
            #pragma unroll
            for (int ht = 0; ht < 4; ++ht) {
                short8 bv = *(const short8*)(vp + (size_t)ht * 16 * TT + kt * 32);
                oacc[ht] = __builtin_amdgcn_mfma_f32_16x16x32_bf16(pa, bv, oacc[ht], 0, 0, 0);
            }
        }
        __builtin_amdgcn_s_setprio(0);

        float inv[4];
        #pragma unroll
        for (int r = 0; r < 4; ++r) inv[r] = 1.0f / psum[r];
        float* op = out + (bbase + i0 + lg * 4) * HH + l15;
        #pragma unroll
        for (int ht = 0; ht < 4; ++ht)
            #pragma unroll
            for (int r = 0; r < 4; ++r)
                op[(size_t)r * HH + ht * 16] = oacc[ht][r] * inv[r];
    } else {
        const int NS = (i0 >> 4) + 1;
        const int NK = (NS + 1) >> 1;
        const int dbase = i0 + lg * 4 - l15;
        const unsigned short* kp = kb + (bbase + l15) * HH + lg * 8;

        for (int ts = 0; ts < NS; ++ts) {
            short8 b0 = *(const short8*)(kp);
            short8 b1 = *(const short8*)(kp + 32);
            kp += 16 * HH;
            f32x4 s = (f32x4){0.f, 0.f, 0.f, 0.f};
            s = __builtin_amdgcn_mfma_f32_16x16x32_bf16(af0, b0, s, 0, 0, 0);
            s = __builtin_amdgcn_mfma_f32_16x16x32_bf16(af1, b1, s, 0, 0, 0);
            const int d0 = dbase - ts * 16;
            #pragma unroll
            for (int r = 0; r < 4; ++r) {
                const int d = d0 + r;
                float sv = s[r] * 0.125f - dec * (float)d - 12.0f;
                float p  = (d < 0) ? 0.0f : __expf(sv);
                psum[r] += p;
                Pw[(lg * 4 + r) * 168 + ts * 16 + l15] = f2bf(p);
            }
        }
        if (NS & 1) {
            #pragma unroll
            for (int r = 0; r < 4; ++r)
                Pw[(lg * 4 + r) * 168 + NS * 16 + l15] = 0;
        }
        #pragma unroll
        for (int off = 1; off < 16; off <<= 1)
            #pragma unroll
            for (int r = 0; r < 4; ++r)
                psum[r] += __shfl_xor(psum[r], off, 64);

        asm volatile("s_waitcnt lgkmcnt(0)" ::: "memory");
        __builtin_amdgcn_sched_barrier(0);

        f32x4 oacc[4];
        #pragma unroll
        for (int ht = 0; ht < 4; ++ht) oacc[ht] = (f32x4){0.f, 0.f, 0.f, 0.f};
        const unsigned short* vp = vt + ((size_t)(gb * 64) + l15) * TT + lg * 8;

        for (int kt = 0; kt < NK; ++kt) {
            short8 pa = *(const short8*)((const char*)Pw + l15 * 336 + kt * 64 + lg * 16);
            #pragma unroll
            for (int ht = 0; ht < 4; ++ht) {
                short8 bv = *(const short8*)(vp + (size_t)ht * 16 * TT + kt * 32);
                oacc[ht] = __builtin_amdgcn_mfma_f32_16x16x32_bf16(pa, bv, oacc[ht], 0, 0, 0);
            }
        }

        float inv[4];
        #pragma unroll
        for (int r = 0; r < 4; ++r) inv[r] = 1.0f / psum[r];
        float* op = out + (bbase + i0 + lg * 4) * HH + l15;
        #pragma unroll
        for (int ht = 0; ht < 4; ++ht)
            #pragma unroll
            for (int r = 0; r < 4; ++r)
                op[(size_t)r * HH + ht * 16] = oacc[ht][r] * inv[r];
    }
}

extern "C" void kernel_launch(void* const* d_in, const int* in_sizes, int n_in,
                              void* d_out, int out_size, void* d_ws, size_t ws_size,
                              hipStream_t stream) {
    const float* x     = (const float*)d_in[0];
    const float* Wq    = (const float*)d_in[1];
    const float* Wk    = (const float*)d_in[2];
    const float* Wv    = (const float*)d_in[3];
    const float* decay = (const float*)d_in[4];
    float* out = (float*)d_out;

    unsigned short* qb  = (unsigned short*)d_ws;          // 2 MB
    unsigned short* kb  = qb + (size_t)MM * HH;           // 2 MB
    unsigned short* vt  = kb + (size_t)MM * HH;           // 2 MB (transposed)
    unsigned short* wtb = vt + (size_t)MM * HH;           // 384 KB

    convw_kernel<<<48, 256, 0, stream>>>(Wq, Wk, Wv, wtb);
    gemm_kernel<<<MM / 64, 256, 0, stream>>>(x, wtb, qb, kb, vt);
    attn_kernel<<<MM / 64, 256, 0, stream>>>(qb, kb, vt, decay, out);
}

// Round 8
// 44.604 us; speedup vs baseline: 1.6635x; 1.0311x over previous
//
#include <hip/hip_runtime.h>
#include <math.h>

#define BB 4
#define TT 4096
#define CC 1024
#define HH 64
#define MM (BB*TT)

typedef __attribute__((ext_vector_type(8))) short  short8;
typedef __attribute__((ext_vector_type(4))) short  short4v;
typedef __attribute__((ext_vector_type(4))) float  f32x4;

typedef const __attribute__((address_space(1))) unsigned int GU;
typedef __attribute__((address_space(3))) unsigned int LU;

static __device__ __forceinline__ unsigned short f2bf(float f) {
    union { float f; unsigned u; } v; v.f = f;
    unsigned r = v.u + 0x7FFF + ((v.u >> 16) & 1);
    return (unsigned short)(r >> 16);
}

// ---------------- Kernel 0: W -> W^T bf16 (tiny) ----------------
__global__ __launch_bounds__(256) void convw_kernel(
        const float* __restrict__ Wq, const float* __restrict__ Wk,
        const float* __restrict__ Wv, unsigned short* __restrict__ wtb) {
    __shared__ unsigned short sW[64][66];
    const int m    = blockIdx.x >> 4;
    const int cblk = blockIdx.x & 15;
    const float* W = (m == 0) ? Wq : (m == 1) ? Wk : Wv;
    const int lane = threadIdx.x & 63;
    const int w    = threadIdx.x >> 6;
    #pragma unroll
    for (int rep = 0; rep < 16; ++rep) {
        const int cl = w * 16 + rep;
        sW[cl][lane] = f2bf(W[(size_t)(cblk * 64 + cl) * HH + lane]);
    }
    __syncthreads();
    #pragma unroll
    for (int rep = 0; rep < 16; ++rep) {
        const int h2 = w * 16 + rep;
        wtb[(size_t)(m * 64 + h2) * CC + cblk * 64 + lane] = sW[lane][h2];
    }
}

// ---------------- Kernel 1: K-split partial projection -------------------
// grid (512, 2): blockIdx.x = 32-row tile, blockIdx.y = K-half (512).
// BM=32, BN=192, BK=64, 8 drain steps. 256 thr = 4 waves (wave = 48 cols).
// LDS 32 KB -> 4 blocks/CU: other blocks' bursts cover each drain window.
// A: fp32 global_load_lds, 16-slot XOR swizzle on global source (r7-verified).
// B: bf16 global_load_lds, 8-slot XOR swizzle (r2/r7-verified).
// Partials fp32: pqk[h][row][128] (q|k), pvt[h][b*64+hh][t] (v, transposed).
__global__ __launch_bounds__(256, 4) void gemmp_kernel(
        const float* __restrict__ x,
        const unsigned short* __restrict__ wtb,
        float* __restrict__ pqk,
        float* __restrict__ pvt) {
    __shared__ float          As[32 * 64];    // 8 KB fp32, row = 256 B
    __shared__ unsigned short Bs[192 * 64];   // 24 KB bf16, row = 128 B

    const int tid  = threadIdx.x;
    const int lane = tid & 63;
    const int w    = tid >> 6;
    const int l15  = lane & 15;
    const int lg   = lane >> 4;
    const int row0 = blockIdx.x * 32;
    const int kc0  = blockIdx.y * 512;

    f32x4 acc[2][3];
    #pragma unroll
    for (int i = 0; i < 2; ++i)
        #pragma unroll
        for (int j = 0; j < 3; ++j)
            acc[i][j] = (f32x4){0.f, 0.f, 0.f, 0.f};

    // A staging: pass p row r = p*16 + (tid>>4); LDS slot (tid&15) holds
    // global slot (tid&15) ^ (r&15); r&15 == tid>>4 for both passes.
    const int arow_local = tid >> 4;
    const int aslot      = (tid & 15) ^ arow_local;
    const float* asrc0   = x + (size_t)(row0 + arow_local) * CC + kc0 + aslot * 4;

    const int bbyte0 = tid * 16;
    const int swz    = (l15 & 7) << 4;

    for (int kc = 0; kc < 512; kc += 64) {
        // ---- stage A: 8 KB fp32, 2 DMA passes ----
        #pragma unroll
        for (int p = 0; p < 2; ++p) {
            const float* g = asrc0 + (size_t)p * 16 * CC + kc;
            __builtin_amdgcn_global_load_lds((GU*)g,
                (LU*)((char*)As + p * 4096 + w * 1024), 16, 0, 0);
        }
        // ---- stage B: 24 KB bf16, 6 DMA passes ----
        #pragma unroll
        for (int it = 0; it < 6; ++it) {
            const int lidx = it * 4096 + bbyte0;
            const int r  = lidx >> 7;
            const int cb = (((lidx & 127) >> 4) ^ (r & 7));
            const unsigned short* g = wtb + (size_t)r * CC + kc0 + kc + cb * 8;
            __builtin_amdgcn_global_load_lds((GU*)g,
                (LU*)((char*)Bs + it * 4096 + w * 1024), 16, 0, 0);
        }
        __syncthreads();   // drain: tile ready

        const char* Asc = (const char*)As;
        const char* Bsc = (const char*)Bs;

        short8 af[2][2];
        #pragma unroll
        for (int mf = 0; mf < 2; ++mf)
            #pragma unroll
            for (int kh = 0; kh < 2; ++kh) {
                const int r    = mf * 16 + l15;
                const int l16  = kh * 8 + lg * 2;
                const int pos0 = l16 ^ l15;
                const float4 lo = *(const float4*)(Asc + r * 256 + pos0 * 16);
                const float4 hi = *(const float4*)(Asc + r * 256 + (pos0 ^ 1) * 16);
                short8 a;
                a[0] = (short)f2bf(lo.x); a[1] = (short)f2bf(lo.y);
                a[2] = (short)f2bf(lo.z); a[3] = (short)f2bf(lo.w);
                a[4] = (short)f2bf(hi.x); a[5] = (short)f2bf(hi.y);
                a[6] = (short)f2bf(hi.z); a[7] = (short)f2bf(hi.w);
                af[mf][kh] = a;
            }
        short8 bf[3][2];
        #pragma unroll
        for (int nf = 0; nf < 3; ++nf)
            #pragma unroll
            for (int kh = 0; kh < 2; ++kh) {
                const int n = w * 48 + nf * 16 + l15;
                bf[nf][kh] = *(const short8*)(Bsc + n * 128 + ((kh * 64 + lg * 16) ^ swz));
            }
        #pragma unroll
        for (int kh = 0; kh < 2; ++kh)
            #pragma unroll
            for (int mf = 0; mf < 2; ++mf)
                #pragma unroll
                for (int nf = 0; nf < 3; ++nf)
                    acc[mf][nf] = __builtin_amdgcn_mfma_f32_16x16x32_bf16(
                        af[mf][kh], bf[nf][kh], acc[mf][nf], 0, 0, 0);
        __syncthreads();   // protect LDS before next DMA
    }

    // ---- epilogue: fp32 partials ----
    const int b = row0 >> 12;
    float* pq = pqk + (size_t)blockIdx.y * MM * 128;
    float* pv = pvt + (size_t)blockIdx.y * 256 * 4096;
    #pragma unroll
    for (int mf = 0; mf < 2; ++mf)
        #pragma unroll
        for (int nf = 0; nf < 3; ++nf) {
            const int ng = w * 48 + nf * 16 + l15;
            const int rowbase = row0 + mf * 16 + lg * 4;
            if (ng < 128) {
                #pragma unroll
                for (int r = 0; r < 4; ++r)
                    pq[(size_t)(rowbase + r) * 128 + ng] = acc[mf][nf][r];
            } else {
                const int hh = ng - 128;
                *reinterpret_cast<f32x4*>(
                    pv + ((size_t)(b * 64 + hh)) * 4096 + (rowbase & 4095)) = acc[mf][nf];
            }
        }
}

// ---------------- Kernel 1b: combine halves -> bf16 q/k/vt ---------------
// blocks [0,2048): qk part, [2048,3072): v part. Fully coalesced streaming.
__global__ __launch_bounds__(256) void combine_kernel(
        const float* __restrict__ pqk, const float* __restrict__ pvt,
        unsigned short* __restrict__ qb, unsigned short* __restrict__ kb,
        unsigned short* __restrict__ vt) {
    const int tid = threadIdx.x;
    if (blockIdx.x < 2048) {
        const int gidx = blockIdx.x * 256 + tid;       // quad over [MM][32]
        const int row = gidx >> 5, qc = gidx & 31;
        const float4 a = *(const float4*)(pqk + (size_t)row * 128 + qc * 4);
        const float4 c = *(const float4*)(pqk + (size_t)MM * 128 + (size_t)row * 128 + qc * 4);
        short4v o;
        o[0] = (short)f2bf(a.x + c.x); o[1] = (short)f2bf(a.y + c.y);
        o[2] = (short)f2bf(a.z + c.z); o[3] = (short)f2bf(a.w + c.w);
        unsigned short* dst = (qc < 16)
            ? (qb + (size_t)row * 64 + qc * 4)
            : (kb + (size_t)row * 64 + (qc - 16) * 4);
        *reinterpret_cast<short4v*>(dst) = o;
    } else {
        const int vidx = (blockIdx.x - 2048) * 256 + tid;  // quad over [256][1024]
        const int hr = vidx >> 10, tq = vidx & 1023;
        const float4 a = *(const float4*)(pvt + (size_t)hr * 4096 + tq * 4);
        const float4 c = *(const float4*)(pvt + (size_t)256 * 4096 + (size_t)hr * 4096 + tq * 4);
        short4v o;
        o[0] = (short)f2bf(a.x + c.x); o[1] = (short)f2bf(a.y + c.y);
        o[2] = (short)f2bf(a.z + c.z); o[3] = (short)f2bf(a.w + c.w);
        *reinterpret_cast<short4v*>(vt + (size_t)hr * 4096 + tq * 4) = o;
    }
}

// ---------------- Kernel 2: MFMA windowed causal attention ----------------
// (unchanged since round 4)
__global__ __launch_bounds__(256) void attn_kernel(
        const unsigned short* __restrict__ qb,
        const unsigned short* __restrict__ kb,
        const unsigned short* __restrict__ vt,
        const float* __restrict__ decay,
        float* __restrict__ out) {
    __shared__ unsigned short P[4][16 * 168];

    const int lane = threadIdx.x & 63;
    const int w    = threadIdx.x >> 6;
    const int l15  = lane & 15;
    const int lg   = lane >> 4;
    const int qt   = blockIdx.x * 4 + w;
    const int gb   = qt >> 8;
    const int i0   = (qt & 255) << 4;

    const float dec = fabsf(decay[0]);
    const size_t bbase = (size_t)gb * TT;

    short8 af0, af1;
    {
        const unsigned short* qp = qb + (bbase + i0 + l15) * HH + lg * 8;
        af0 = *(const short8*)(qp);
        af1 = *(const short8*)(qp + 32);
    }

    float psum[4] = {0.f, 0.f, 0.f, 0.f};
    unsigned short* Pw = &P[w][0];

    if (i0 >= 144) {
        const int js = i0 - 144;
        const unsigned short* kp = kb + (bbase + js + l15) * HH + lg * 8;
        #pragma unroll
        for (int ts = 0; ts < 10; ++ts) {
            short8 b0 = *(const short8*)(kp + (size_t)ts * 16 * HH);
            short8 b1 = *(const short8*)(kp + (size_t)ts * 16 * HH + 32);
            f32x4 s = (f32x4){0.f, 0.f, 0.f, 0.f};
            s = __builtin_amdgcn_mfma_f32_16x16x32_bf16(af0, b0, s, 0, 0, 0);
            s = __builtin_amdgcn_mfma_f32_16x16x32_bf16(af1, b1, s, 0, 0, 0);
            const int d0 = 144 + lg * 4 - ts * 16 - l15;
            #pragma unroll
            for (int r = 0; r < 4; ++r) {
                const int d = d0 + r;
                float sv = s[r] * 0.125f - dec * (float)d - 12.0f;
                float p  = (ts == 9 && d < 0) ? 0.0f : __expf(sv);
                psum[r] += p;
                Pw[(lg * 4 + r) * 168 + ts * 16 + l15] = f2bf(p);
            }
        }
        #pragma unroll
        for (int off = 1; off < 16; off <<= 1)
            #pragma unroll
            for (int r = 0; r < 4; ++r)
                psum[r] += __shfl_xor(psum[r], off, 64);

        asm volatile("s_waitcnt lgkmcnt(0)" ::: "memory");
        __builtin_amdgcn_sched_barrier(0);

        f32x4 oacc[4];
        #pragma unroll
        for (int ht = 0; ht < 4; ++ht) oacc[ht] = (f32x4){0.f, 0.f, 0.f, 0.f};
        const unsigned short* vp = vt + ((size_t)(gb * 64) + l15) * TT + js + lg * 8;

        __builtin_amdgcn_s_setprio(1);
        #pragma unroll
        for (int kt = 0; kt < 5; ++kt) {
            short8 pa = *(const short8*)((const char*)Pw + l15 * 336 + kt * 64 + lg * 16);
            #pragma unroll
            for (int ht = 0; ht < 4; ++ht) {
                short8 bv = *(const short8*)(vp + (size_t)ht * 16 * TT + kt * 32);
                oacc[ht] = __builtin_amdgcn_mfma_f32_16x16x32_bf16(pa, bv, oacc[ht], 0, 0, 0);
            }
        }
        __builtin_amdgcn_s_setprio(0);

        float inv[4];
        #pragma unroll
        for (int r = 0; r < 4; ++r) inv[r] = 1.0f / psum[r];
        float* op = out + (bbase + i0 + lg * 4) * HH + l15;
        #pragma unroll
        for (int ht = 0; ht < 4; ++ht)
            #pragma unroll
            for (int r = 0; r < 4; ++r)
                op[(size_t)r * HH + ht * 16] = oacc[ht][r] * inv[r];
    } else {
        const int NS = (i0 >> 4) + 1;
        const int NK = (NS + 1) >> 1;
        const int dbase = i0 + lg * 4 - l15;
        const unsigned short* kp = kb + (bbase + l15) * HH + lg * 8;

        for (int ts = 0; ts < NS; ++ts) {
            short8 b0 = *(const short8*)(kp);
            short8 b1 = *(const short8*)(kp + 32);
            kp += 16 * HH;
            f32x4 s = (f32x4){0.f, 0.f, 0.f, 0.f};
            s = __builtin_amdgcn_mfma_f32_16x16x32_bf16(af0, b0, s, 0, 0, 0);
            s = __builtin_amdgcn_mfma_f32_16x16x32_bf16(af1, b1, s, 0, 0, 0);
            const int d0 = dbase - ts * 16;
            #pragma unroll
            for (int r = 0; r < 4; ++r) {
                const int d = d0 + r;
                float sv = s[r] * 0.125f - dec * (float)d - 12.0f;
                float p  = (d < 0) ? 0.0f : __expf(sv);
                psum[r] += p;
                Pw[(lg * 4 + r) * 168 + ts * 16 + l15] = f2bf(p);
            }
        }
        if (NS & 1) {
            #pragma unroll
            for (int r = 0; r < 4; ++r)
                Pw[(lg * 4 + r) * 168 + NS * 16 + l15] = 0;
        }
        #pragma unroll
        for (int off = 1; off < 16; off <<= 1)
            #pragma unroll
            for (int r = 0; r < 4; ++r)
                psum[r] += __shfl_xor(psum[r], off, 64);

        asm volatile("s_waitcnt lgkmcnt(0)" ::: "memory");
        __builtin_amdgcn_sched_barrier(0);

        f32x4 oacc[4];
        #pragma unroll
        for (int ht = 0; ht < 4; ++ht) oacc[ht] = (f32x4){0.f, 0.f, 0.f, 0.f};
        const unsigned short* vp = vt + ((size_t)(gb * 64) + l15) * TT + lg * 8;

        for (int kt = 0; kt < NK; ++kt) {
            short8 pa = *(const short8*)((const char*)Pw + l15 * 336 + kt * 64 + lg * 16);
            #pragma unroll
            for (int ht = 0; ht < 4; ++ht) {
                short8 bv = *(const short8*)(vp + (size_t)ht * 16 * TT + kt * 32);
                oacc[ht] = __builtin_amdgcn_mfma_f32_16x16x32_bf16(pa, bv, oacc[ht], 0, 0, 0);
            }
        }

        float inv[4];
        #pragma unroll
        for (int r = 0; r < 4; ++r) inv[r] = 1.0f / psum[r];
        float* op = out + (bbase + i0 + lg * 4) * HH + l15;
        #pragma unroll
        for (int ht = 0; ht < 4; ++ht)
            #pragma unroll
            for (int r = 0; r < 4; ++r)
                op[(size_t)r * HH + ht * 16] = oacc[ht][r] * inv[r];
    }
}

extern "C" void kernel_launch(void* const* d_in, const int* in_sizes, int n_in,
                              void* d_out, int out_size, void* d_ws, size_t ws_size,
                              hipStream_t stream) {
    const float* x     = (const float*)d_in[0];
    const float* Wq    = (const float*)d_in[1];
    const float* Wk    = (const float*)d_in[2];
    const float* Wv    = (const float*)d_in[3];
    const float* decay = (const float*)d_in[4];
    float* out = (float*)d_out;

    float* pqk = (float*)d_ws;                               // [2][MM][128] 16 MB
    float* pvt = pqk + (size_t)2 * MM * 128;                 // [2][256][4096] 8 MB
    unsigned short* qb  = (unsigned short*)(pvt + (size_t)2 * 256 * 4096); // 2 MB
    unsigned short* kb  = qb + (size_t)MM * HH;              // 2 MB
    unsigned short* vt  = kb + (size_t)MM * HH;              // 2 MB
    unsigned short* wtb = vt + (size_t)MM * HH;              // 384 KB

    convw_kernel<<<48, 256, 0, stream>>>(Wq, Wk, Wv, wtb);
    gemmp_kernel<<<dim3(512, 2), 256, 0, stream>>>(x, wtb, pqk, pvt);
    combine_kernel<<<3072, 256, 0, stream>>>(pqk, pvt, qb, kb, vt);
    attn_kernel<<<MM / 64, 256, 0, stream>>>(qb, kb, vt, decay, out);
}